// Round 9
// baseline (117.598 us; speedup 1.0000x reference)
//
#include <hip/hip_runtime.h>
#include <stdint.h>

// BiasAddLayerNormFP8: bda = residual + (x + bias); LayerNorm over H=1024;
// outputs: [bda2 f32 | fp8(ln) dequantized to f32 | amax scalar], all float32.
//
// R9: async DMA staging. One wave per block; 16KB LDS double-buffer per wave.
// global_load_lds keeps 8KB/wave of reads in flight with ZERO VGPR cost
// (register-staged MLP capped at ~4.6 TB/s across R3-R8: allocator refuses
// >64 VGPR of load buffers). Counted s_waitcnt vmcnt(16) -- never drained to
// 0 in the loop -- releases row t's DMAs while row t+1's DMAs + row t-1's
// stores stay in flight. bias/gamma/beta hoisted to registers so in-loop
// vmcnt ops are exactly 8 DMA + 8 stores. No barriers (wave-private LDS).
// Reduce/quant numerics bit-identical to the passing R2/R5/R8 chain.

constexpr int H = 1024;
constexpr int CHUNKS = 4;            // 4 x float4 x 64 lanes = 1024 cols
constexpr float EPS = 1e-5f;
constexpr float FP8_MAX = 448.0f;
constexpr float INV_H = 1.0f / 1024.0f;

__device__ __forceinline__ float waveReduceMax(float v) {
#pragma unroll
    for (int off = 32; off > 0; off >>= 1) v = fmaxf(v, __shfl_down(v, off));
    return v;
}

// 16B/lane direct global->LDS DMA. LDS dest is wave-uniform base + lane*16;
// global src is per-lane. (guide §5: width=16 emits global_load_lds_dwordx4)
__device__ __forceinline__ void dma16(const float* g, float* l) {
    __builtin_amdgcn_global_load_lds(
        (const __attribute__((address_space(1))) void*)g,
        (__attribute__((address_space(3))) void*)l,
        16, 0, 0);
}

// Stage one row's x and residual (8 x 1KB DMA ops) into an LDS buffer half.
__device__ __forceinline__ void dmaRow(
    const float* __restrict__ x, const float* __restrict__ residual,
    size_t rowBase, float* ldsBuf, int lane)
{
#pragma unroll
    for (int c = 0; c < CHUNKS; ++c)
        dma16(x + rowBase + c * 256 + lane * 4, ldsBuf + c * 256);
#pragma unroll
    for (int c = 0; c < CHUNKS; ++c)
        dma16(residual + rowBase + c * 256 + lane * 4, ldsBuf + 1024 + c * 256);
}

__global__ __launch_bounds__(64) void fused_bda_ln_fp8_dma(
    const float* __restrict__ x,
    const float* __restrict__ bias,
    const float* __restrict__ residual,
    const float* __restrict__ gamma,
    const float* __restrict__ beta,
    float* __restrict__ out_bda,
    float* __restrict__ out_q,
    unsigned int* __restrict__ out_amax,
    int n_rows)
{
    __shared__ float smem[4096];     // [2 buffers][x:1024 | r:1024] = 16KB
    const int lane = (int)threadIdx.x;   // 64 threads = 1 wave
    const int gw = (int)blockIdx.x;      // one wave per block
    const int gwaves = (int)gridDim.x;

    // Hoist per-lane-constant params to registers: keeps the loop's vmcnt
    // population exactly {8 DMA, 8 stores} and removes redundant L1 reads.
    float4 bv[CHUNKS], gv[CHUNKS], tv[CHUNKS];
#pragma unroll
    for (int c = 0; c < CHUNKS; ++c) {
        const int col = lane * 4 + c * 256;
        bv[c] = *reinterpret_cast<const float4*>(bias + col);
        gv[c] = *reinterpret_cast<const float4*>(gamma + col);
        tv[c] = *reinterpret_cast<const float4*>(beta + col);
    }

    float localAmax = 0.0f;
    int cur = 0;

    // prologue: stage first row, drain once (only full drain in the kernel)
    if (gw < n_rows)
        dmaRow(x, residual, (size_t)gw * H, smem, lane);
    asm volatile("s_waitcnt vmcnt(0)" ::: "memory");
    __builtin_amdgcn_sched_barrier(0);

#pragma unroll 1
    for (int row = gw; row < n_rows; row += gwaves) {
        const int nxt = row + gwaves;
        if (nxt < n_rows) {
            // issue next row's 8 DMAs into the other buffer, then a COUNTED
            // wait: <=16 outstanding (= these 8 DMAs + prev iter's 8 stores)
            // guarantees THIS row's DMAs (older) completed, without draining.
            dmaRow(x, residual, (size_t)nxt * H, smem + (cur ^ 1) * 2048, lane);
            asm volatile("s_waitcnt vmcnt(16)" ::: "memory");
        } else {
            // last row: outstanding = this row's 8 DMAs (oldest) + 8 stores
            asm volatile("s_waitcnt vmcnt(8)" ::: "memory");
        }
        __builtin_amdgcn_sched_barrier(0);   // rule 18: pin ds_reads below wait

        const size_t b = (size_t)row * H;
        const float4* lx = reinterpret_cast<const float4*>(smem + cur * 2048);
        const float4* lr = reinterpret_cast<const float4*>(smem + cur * 2048 + 1024);

        // ---- bda + row sum (same association as reference / R2 chain) ----
        float A[CHUNKS][4];
        float s = 0.0f;
#pragma unroll
        for (int c = 0; c < CHUNKS; ++c) {
            const float4 xv = lx[c * 64 + lane];   // ds_read_b128
            const float4 rv = lr[c * 64 + lane];
            A[c][0] = rv.x + (xv.x + bv[c].x);
            A[c][1] = rv.y + (xv.y + bv[c].y);
            A[c][2] = rv.z + (xv.z + bv[c].z);
            A[c][3] = rv.w + (xv.w + bv[c].w);
            *reinterpret_cast<float4*>(out_bda + b + lane * 4 + c * 256) =
                make_float4(A[c][0], A[c][1], A[c][2], A[c][3]);
            s += (A[c][0] + A[c][1]) + (A[c][2] + A[c][3]);
        }

        // ---- mean (wave-synchronous butterfly) ----
#pragma unroll
        for (int off = 1; off < 64; off <<= 1) s += __shfl_xor(s, off);
        const float mu = s * INV_H;

        // ---- variance, two-pass (bit-identical to passing chain) ----
        float ss = 0.0f;
#pragma unroll
        for (int c = 0; c < CHUNKS; ++c) {
#pragma unroll
            for (int j = 0; j < 4; ++j) {
                A[c][j] -= mu;
                ss += A[c][j] * A[c][j];
            }
        }
#pragma unroll
        for (int off = 1; off < 64; off <<= 1) ss += __shfl_xor(ss, off);
        const float rsigma = 1.0f / sqrtf(ss * INV_H + EPS);

        // ---- normalize + affine + fp8 quant/dequant + store ----
#pragma unroll
        for (int c = 0; c < CHUNKS; ++c) {
            const float l0 = A[c][0] * rsigma * gv[c].x + tv[c].x;
            const float l1 = A[c][1] * rsigma * gv[c].y + tv[c].y;
            const float l2 = A[c][2] * rsigma * gv[c].z + tv[c].z;
            const float l3 = A[c][3] * rsigma * gv[c].w + tv[c].w;

            localAmax = fmaxf(localAmax,
                fmaxf(fmaxf(fabsf(l0), fabsf(l1)), fmaxf(fabsf(l2), fabsf(l3))));

            const float c0 = fminf(fmaxf(l0, -FP8_MAX), FP8_MAX);
            const float c1 = fminf(fmaxf(l1, -FP8_MAX), FP8_MAX);
            const float c2 = fminf(fmaxf(l2, -FP8_MAX), FP8_MAX);
            const float c3 = fminf(fmaxf(l3, -FP8_MAX), FP8_MAX);
            const int p01 = __builtin_amdgcn_cvt_pk_fp8_f32(c0, c1, 0, false);
            const int p23 = __builtin_amdgcn_cvt_pk_fp8_f32(c2, c3, 0, false);
            float4 qv;
            qv.x = __builtin_amdgcn_cvt_f32_fp8(p01, 0);
            qv.y = __builtin_amdgcn_cvt_f32_fp8(p01, 1);
            qv.z = __builtin_amdgcn_cvt_f32_fp8(p23, 0);
            qv.w = __builtin_amdgcn_cvt_f32_fp8(p23, 1);
            *reinterpret_cast<float4*>(out_q + b + lane * 4 + c * 256) = qv;
        }

        cur ^= 1;
    }

    // ---- wave amax -> one device-scope atomic per block ----
    const float m = waveReduceMax(localAmax);
    if (lane == 0) atomicMax(out_amax, __float_as_uint(m));   // values >= 0
}

extern "C" void kernel_launch(void* const* d_in, const int* in_sizes, int n_in,
                              void* d_out, int out_size, void* d_ws, size_t ws_size,
                              hipStream_t stream) {
    const float* x        = (const float*)d_in[0];
    const float* bias     = (const float*)d_in[1];
    const float* residual = (const float*)d_in[2];
    const float* gamma    = (const float*)d_in[3];
    const float* beta     = (const float*)d_in[4];

    const int n_elems = in_sizes[0];          // B*S*H
    const int n_rows = n_elems / H;           // 32768

    float* out_bda = (float*)d_out;
    float* out_q   = out_bda + (size_t)n_elems;
    unsigned int* out_amax = (unsigned int*)(out_bda + 2 * (size_t)n_elems);

    // zero the amax slot each launch (deterministic across graph replays)
    hipMemsetAsync((void*)out_amax, 0, sizeof(unsigned int), stream);

    // 2048 single-wave blocks -> exactly 16 rows per wave (perfect balance);
    // 16KB LDS/block -> 8 blocks/CU; 8 waves x 8KB DMA in flight per CU.
    int blocks = n_rows < 2048 ? n_rows : 2048;
    if (blocks < 1) blocks = 1;

    fused_bda_ln_fp8_dma<<<blocks, 64, 0, stream>>>(
        x, bias, residual, gamma, beta, out_bda, out_q, out_amax, n_rows);
}

// Round 10
// 103.295 us; speedup vs baseline: 1.1385x; 1.1385x over previous
//
#include <hip/hip_runtime.h>

// BiasAddLayerNormFP8: bda = residual + (x + bias); LayerNorm over H=1024;
// outputs: [bda2 f32 | fp8(ln) dequantized to f32 | amax scalar], all float32.
//
// R10: R8's structure (2-row straight-line, 2048 blocks, 32 waves/CU)
// + non-temporal loads/stores on all four streamed 256MB streams.
// Theory: 512MB once-touched data churns L2/L3 (write-allocate evicts
// everything); NT keeps streams out of cache. Single-variable A/B vs R8's
// 112.4us. Values are bit-identical (cache policy only); bias/gamma/beta
// remain cached (hot, reused).

constexpr int H = 1024;
constexpr int CHUNKS = 4;            // 4 x float4 x 64 lanes = 1024 cols
constexpr float EPS = 1e-5f;
constexpr float FP8_MAX = 448.0f;
constexpr float INV_H = 1.0f / 1024.0f;

typedef float f32x4 __attribute__((ext_vector_type(4)));

__device__ __forceinline__ float waveAllReduceSum(float v) {
#pragma unroll
    for (int off = 1; off < 64; off <<= 1) v += __shfl_xor(v, off);
    return v;
}

__device__ __forceinline__ float waveReduceMax(float v) {
#pragma unroll
    for (int off = 32; off > 0; off >>= 1) v = fmaxf(v, __shfl_down(v, off));
    return v;
}

__device__ __forceinline__ f32x4 ntLoad4(const float* p) {
    return __builtin_nontemporal_load(reinterpret_cast<const f32x4*>(p));
}
__device__ __forceinline__ void ntStore4(float* p, float a, float b, float c, float d) {
    f32x4 v = {a, b, c, d};
    __builtin_nontemporal_store(v, reinterpret_cast<f32x4*>(p));
}

__device__ __forceinline__ void quantChunk(
    const float (&d)[4], float rsigma, const float4& gv, const float4& tv,
    float* __restrict__ dst, float& localAmax)
{
    const float l0 = d[0] * rsigma * gv.x + tv.x;
    const float l1 = d[1] * rsigma * gv.y + tv.y;
    const float l2 = d[2] * rsigma * gv.z + tv.z;
    const float l3 = d[3] * rsigma * gv.w + tv.w;

    localAmax = fmaxf(localAmax,
        fmaxf(fmaxf(fabsf(l0), fabsf(l1)), fmaxf(fabsf(l2), fabsf(l3))));

    const float c0 = fminf(fmaxf(l0, -FP8_MAX), FP8_MAX);
    const float c1 = fminf(fmaxf(l1, -FP8_MAX), FP8_MAX);
    const float c2 = fminf(fmaxf(l2, -FP8_MAX), FP8_MAX);
    const float c3 = fminf(fmaxf(l3, -FP8_MAX), FP8_MAX);
    const int p01 = __builtin_amdgcn_cvt_pk_fp8_f32(c0, c1, 0, false);
    const int p23 = __builtin_amdgcn_cvt_pk_fp8_f32(c2, c3, 0, false);
    ntStore4(dst,
             __builtin_amdgcn_cvt_f32_fp8(p01, 0),
             __builtin_amdgcn_cvt_f32_fp8(p01, 1),
             __builtin_amdgcn_cvt_f32_fp8(p23, 0),
             __builtin_amdgcn_cvt_f32_fp8(p23, 1));
}

// Single-row path (tail only; never runs for even n_rows). Same numerics.
__device__ __forceinline__ void processOneRow(
    int row, int col0,
    const float* __restrict__ x, const float* __restrict__ residual,
    const float* __restrict__ bias, const float* __restrict__ gamma,
    const float* __restrict__ beta,
    float* __restrict__ out_bda, float* __restrict__ out_q, float& localAmax)
{
    const size_t rbase = (size_t)row * H;
    float bda[CHUNKS][4];
    float s = 0.0f;
#pragma unroll
    for (int c = 0; c < CHUNKS; ++c) {
        const int col = col0 + c * 256;
        const f32x4 xv = ntLoad4(x + rbase + col);
        const f32x4 rv = ntLoad4(residual + rbase + col);
        const float4 bv = *reinterpret_cast<const float4*>(bias + col);
        bda[c][0] = rv.x + (xv.x + bv.x);
        bda[c][1] = rv.y + (xv.y + bv.y);
        bda[c][2] = rv.z + (xv.z + bv.z);
        bda[c][3] = rv.w + (xv.w + bv.w);
        ntStore4(out_bda + rbase + col, bda[c][0], bda[c][1], bda[c][2], bda[c][3]);
        s += (bda[c][0] + bda[c][1]) + (bda[c][2] + bda[c][3]);
    }
    const float mu = waveAllReduceSum(s) * INV_H;
    float ss = 0.0f;
#pragma unroll
    for (int c = 0; c < CHUNKS; ++c)
#pragma unroll
        for (int j = 0; j < 4; ++j) { bda[c][j] -= mu; ss += bda[c][j] * bda[c][j]; }
    ss = waveAllReduceSum(ss);
    const float rsigma = 1.0f / sqrtf(ss * INV_H + EPS);
#pragma unroll
    for (int c = 0; c < CHUNKS; ++c) {
        const int col = col0 + c * 256;
        const float4 gv = *reinterpret_cast<const float4*>(gamma + col);
        const float4 tv = *reinterpret_cast<const float4*>(beta + col);
        quantChunk(bda[c], rsigma, gv, tv, out_q + rbase + col, localAmax);
    }
}

__global__ __launch_bounds__(256, 4) void fused_bda_ln_fp8(
    const float* __restrict__ x,
    const float* __restrict__ bias,
    const float* __restrict__ residual,
    const float* __restrict__ gamma,
    const float* __restrict__ beta,
    float* __restrict__ out_bda,
    float* __restrict__ out_q,
    unsigned int* __restrict__ out_amax,
    int n_rows)
{
    const int tid = threadIdx.x;      // 256 threads = 4 waves
    const int lane = tid & 63;
    const int wid = tid >> 6;
    const int col0 = lane * 4;
    const int gw = blockIdx.x * 4 + wid;     // global wave id
    const int gwaves = gridDim.x * 4;

    float localAmax = 0.0f;
    __shared__ float red[4];

    const int pairs = n_rows >> 1;

#pragma unroll 1
    for (int p = gw; p < pairs; p += gwaves) {
        const size_t b0 = (size_t)(2 * p) * H;
        const size_t b1 = b0 + H;

        // ---- issue ALL 16 loads back-to-back (one basic block, no branches) ----
        f32x4 xa[CHUNKS], ra[CHUNKS], xb[CHUNKS], rb[CHUNKS];
#pragma unroll
        for (int c = 0; c < CHUNKS; ++c) {
            const int col = col0 + c * 256;
            xa[c] = ntLoad4(x + b0 + col);
            ra[c] = ntLoad4(residual + b0 + col);
            xb[c] = ntLoad4(x + b1 + col);
            rb[c] = ntLoad4(residual + b1 + col);
        }

        // ---- consume: bda for both rows (row0's loads complete first) ----
        float A[CHUNKS][4], B[CHUNKS][4];
        float s0 = 0.0f, s1 = 0.0f;
#pragma unroll
        for (int c = 0; c < CHUNKS; ++c) {
            const int col = col0 + c * 256;
            const float4 bv = *reinterpret_cast<const float4*>(bias + col);
            A[c][0] = ra[c].x + (xa[c].x + bv.x);
            A[c][1] = ra[c].y + (xa[c].y + bv.y);
            A[c][2] = ra[c].z + (xa[c].z + bv.z);
            A[c][3] = ra[c].w + (xa[c].w + bv.w);
            B[c][0] = rb[c].x + (xb[c].x + bv.x);
            B[c][1] = rb[c].y + (xb[c].y + bv.y);
            B[c][2] = rb[c].z + (xb[c].z + bv.z);
            B[c][3] = rb[c].w + (xb[c].w + bv.w);
            ntStore4(out_bda + b0 + col, A[c][0], A[c][1], A[c][2], A[c][3]);
            ntStore4(out_bda + b1 + col, B[c][0], B[c][1], B[c][2], B[c][3]);
            s0 += (A[c][0] + A[c][1]) + (A[c][2] + A[c][3]);
            s1 += (B[c][0] + B[c][1]) + (B[c][2] + B[c][3]);
        }

        // ---- mean: two independent butterflies, explicitly interleaved ----
#pragma unroll
        for (int off = 1; off < 64; off <<= 1) {
            s0 += __shfl_xor(s0, off);
            s1 += __shfl_xor(s1, off);
        }
        const float mu0 = s0 * INV_H;
        const float mu1 = s1 * INV_H;

        // ---- variance, two-pass, both rows ----
        float ss0 = 0.0f, ss1 = 0.0f;
#pragma unroll
        for (int c = 0; c < CHUNKS; ++c) {
#pragma unroll
            for (int j = 0; j < 4; ++j) {
                A[c][j] -= mu0; ss0 += A[c][j] * A[c][j];
                B[c][j] -= mu1; ss1 += B[c][j] * B[c][j];
            }
        }
#pragma unroll
        for (int off = 1; off < 64; off <<= 1) {
            ss0 += __shfl_xor(ss0, off);
            ss1 += __shfl_xor(ss1, off);
        }
        const float rs0 = 1.0f / sqrtf(ss0 * INV_H + EPS);
        const float rs1 = 1.0f / sqrtf(ss1 * INV_H + EPS);

        // ---- normalize + affine + fp8 + store; gamma/beta shared per chunk ----
#pragma unroll
        for (int c = 0; c < CHUNKS; ++c) {
            const int col = col0 + c * 256;
            const float4 gv = *reinterpret_cast<const float4*>(gamma + col);
            const float4 tv = *reinterpret_cast<const float4*>(beta + col);
            quantChunk(A[c], rs0, gv, tv, out_q + b0 + col, localAmax);
            quantChunk(B[c], rs1, gv, tv, out_q + b1 + col, localAmax);
        }
    }

    // tail (odd n_rows only; never runs in this benchmark)
    for (int row = 2 * pairs + gw; row < n_rows; row += gwaves)
        processOneRow(row, col0, x, residual, bias, gamma, beta,
                      out_bda, out_q, localAmax);

    // ---- block amax -> one device-scope atomic per block ----
    float m = waveReduceMax(localAmax);
    if (lane == 0) red[wid] = m;
    __syncthreads();
    if (tid == 0) {
        const float bm = fmaxf(fmaxf(red[0], red[1]), fmaxf(red[2], red[3]));
        atomicMax(out_amax, __float_as_uint(bm));   // all values >= 0
    }
}

extern "C" void kernel_launch(void* const* d_in, const int* in_sizes, int n_in,
                              void* d_out, int out_size, void* d_ws, size_t ws_size,
                              hipStream_t stream) {
    const float* x        = (const float*)d_in[0];
    const float* bias     = (const float*)d_in[1];
    const float* residual = (const float*)d_in[2];
    const float* gamma    = (const float*)d_in[3];
    const float* beta     = (const float*)d_in[4];

    const int n_elems = in_sizes[0];          // B*S*H
    const int n_rows = n_elems / H;           // 32768

    float* out_bda = (float*)d_out;
    float* out_q   = out_bda + (size_t)n_elems;
    unsigned int* out_amax = (unsigned int*)(out_bda + 2 * (size_t)n_elems);

    // zero the amax slot each launch (deterministic across graph replays)
    hipMemsetAsync((void*)out_amax, 0, sizeof(unsigned int), stream);

    // 2048 blocks x 4 waves = 8192 waves, 2 rows/wave/iter -> 2 iterations.
    int blocks = (n_rows / 2 + 3) / 4;
    if (blocks > 2048) blocks = 2048;

    fused_bda_ln_fp8<<<blocks, 256, 0, stream>>>(
        x, bias, residual, gamma, beta, out_bda, out_q, out_amax, n_rows);
}

// Round 11
// 90.973 us; speedup vs baseline: 1.2927x; 1.1354x over previous
//
#include <hip/hip_runtime.h>

// BiasAddLayerNormFP8: bda = residual + (x + bias); LayerNorm over H=1024;
// outputs: [bda2 f32 | fp8(ln) dequantized to f32 | amax scalar], all float32.
//
// R11: single-variable A/B vs R10 (103.3us): loads reverted to CACHED
// (L2/L3 aggregation like the 6.29 TB/s copy ubench), stores stay
// NON-TEMPORAL (write-allocate churn on 256MB of once-written lines was
// the R10-confirmed tax). Structure: R8's 2-row straight-line, 2048 blocks,
// 32 waves/CU. Numerics bit-identical to the passing R2/R5/R8/R10 chain.

constexpr int H = 1024;
constexpr int CHUNKS = 4;            // 4 x float4 x 64 lanes = 1024 cols
constexpr float EPS = 1e-5f;
constexpr float FP8_MAX = 448.0f;
constexpr float INV_H = 1.0f / 1024.0f;

typedef float f32x4 __attribute__((ext_vector_type(4)));

__device__ __forceinline__ float waveAllReduceSum(float v) {
#pragma unroll
    for (int off = 1; off < 64; off <<= 1) v += __shfl_xor(v, off);
    return v;
}

__device__ __forceinline__ float waveReduceMax(float v) {
#pragma unroll
    for (int off = 32; off > 0; off >>= 1) v = fmaxf(v, __shfl_down(v, off));
    return v;
}

__device__ __forceinline__ void ntStore4(float* p, float a, float b, float c, float d) {
    f32x4 v = {a, b, c, d};
    __builtin_nontemporal_store(v, reinterpret_cast<f32x4*>(p));
}

__device__ __forceinline__ void quantChunk(
    const float (&d)[4], float rsigma, const float4& gv, const float4& tv,
    float* __restrict__ dst, float& localAmax)
{
    const float l0 = d[0] * rsigma * gv.x + tv.x;
    const float l1 = d[1] * rsigma * gv.y + tv.y;
    const float l2 = d[2] * rsigma * gv.z + tv.z;
    const float l3 = d[3] * rsigma * gv.w + tv.w;

    localAmax = fmaxf(localAmax,
        fmaxf(fmaxf(fabsf(l0), fabsf(l1)), fmaxf(fabsf(l2), fabsf(l3))));

    const float c0 = fminf(fmaxf(l0, -FP8_MAX), FP8_MAX);
    const float c1 = fminf(fmaxf(l1, -FP8_MAX), FP8_MAX);
    const float c2 = fminf(fmaxf(l2, -FP8_MAX), FP8_MAX);
    const float c3 = fminf(fmaxf(l3, -FP8_MAX), FP8_MAX);
    const int p01 = __builtin_amdgcn_cvt_pk_fp8_f32(c0, c1, 0, false);
    const int p23 = __builtin_amdgcn_cvt_pk_fp8_f32(c2, c3, 0, false);
    ntStore4(dst,
             __builtin_amdgcn_cvt_f32_fp8(p01, 0),
             __builtin_amdgcn_cvt_f32_fp8(p01, 1),
             __builtin_amdgcn_cvt_f32_fp8(p23, 0),
             __builtin_amdgcn_cvt_f32_fp8(p23, 1));
}

// Single-row path (tail only; never runs for even n_rows). Same numerics.
__device__ __forceinline__ void processOneRow(
    int row, int col0,
    const float* __restrict__ x, const float* __restrict__ residual,
    const float* __restrict__ bias, const float* __restrict__ gamma,
    const float* __restrict__ beta,
    float* __restrict__ out_bda, float* __restrict__ out_q, float& localAmax)
{
    const size_t rbase = (size_t)row * H;
    float bda[CHUNKS][4];
    float s = 0.0f;
#pragma unroll
    for (int c = 0; c < CHUNKS; ++c) {
        const int col = col0 + c * 256;
        const float4 xv = *reinterpret_cast<const float4*>(x + rbase + col);
        const float4 rv = *reinterpret_cast<const float4*>(residual + rbase + col);
        const float4 bv = *reinterpret_cast<const float4*>(bias + col);
        bda[c][0] = rv.x + (xv.x + bv.x);
        bda[c][1] = rv.y + (xv.y + bv.y);
        bda[c][2] = rv.z + (xv.z + bv.z);
        bda[c][3] = rv.w + (xv.w + bv.w);
        ntStore4(out_bda + rbase + col, bda[c][0], bda[c][1], bda[c][2], bda[c][3]);
        s += (bda[c][0] + bda[c][1]) + (bda[c][2] + bda[c][3]);
    }
    const float mu = waveAllReduceSum(s) * INV_H;
    float ss = 0.0f;
#pragma unroll
    for (int c = 0; c < CHUNKS; ++c)
#pragma unroll
        for (int j = 0; j < 4; ++j) { bda[c][j] -= mu; ss += bda[c][j] * bda[c][j]; }
    ss = waveAllReduceSum(ss);
    const float rsigma = 1.0f / sqrtf(ss * INV_H + EPS);
#pragma unroll
    for (int c = 0; c < CHUNKS; ++c) {
        const int col = col0 + c * 256;
        const float4 gv = *reinterpret_cast<const float4*>(gamma + col);
        const float4 tv = *reinterpret_cast<const float4*>(beta + col);
        quantChunk(bda[c], rsigma, gv, tv, out_q + rbase + col, localAmax);
    }
}

__global__ __launch_bounds__(256, 4) void fused_bda_ln_fp8(
    const float* __restrict__ x,
    const float* __restrict__ bias,
    const float* __restrict__ residual,
    const float* __restrict__ gamma,
    const float* __restrict__ beta,
    float* __restrict__ out_bda,
    float* __restrict__ out_q,
    unsigned int* __restrict__ out_amax,
    int n_rows)
{
    const int tid = threadIdx.x;      // 256 threads = 4 waves
    const int lane = tid & 63;
    const int wid = tid >> 6;
    const int col0 = lane * 4;
    const int gw = blockIdx.x * 4 + wid;     // global wave id
    const int gwaves = gridDim.x * 4;

    float localAmax = 0.0f;
    __shared__ float red[4];

    const int pairs = n_rows >> 1;

#pragma unroll 1
    for (int p = gw; p < pairs; p += gwaves) {
        const size_t b0 = (size_t)(2 * p) * H;
        const size_t b1 = b0 + H;

        // ---- issue ALL 16 loads back-to-back (cached: L2/L3 aggregation) ----
        float4 xa[CHUNKS], ra[CHUNKS], xb[CHUNKS], rb[CHUNKS];
#pragma unroll
        for (int c = 0; c < CHUNKS; ++c) {
            const int col = col0 + c * 256;
            xa[c] = *reinterpret_cast<const float4*>(x + b0 + col);
            ra[c] = *reinterpret_cast<const float4*>(residual + b0 + col);
            xb[c] = *reinterpret_cast<const float4*>(x + b1 + col);
            rb[c] = *reinterpret_cast<const float4*>(residual + b1 + col);
        }

        // ---- consume: bda for both rows (row0's loads complete first) ----
        float A[CHUNKS][4], B[CHUNKS][4];
        float s0 = 0.0f, s1 = 0.0f;
#pragma unroll
        for (int c = 0; c < CHUNKS; ++c) {
            const int col = col0 + c * 256;
            const float4 bv = *reinterpret_cast<const float4*>(bias + col);
            A[c][0] = ra[c].x + (xa[c].x + bv.x);
            A[c][1] = ra[c].y + (xa[c].y + bv.y);
            A[c][2] = ra[c].z + (xa[c].z + bv.z);
            A[c][3] = ra[c].w + (xa[c].w + bv.w);
            B[c][0] = rb[c].x + (xb[c].x + bv.x);
            B[c][1] = rb[c].y + (xb[c].y + bv.y);
            B[c][2] = rb[c].z + (xb[c].z + bv.z);
            B[c][3] = rb[c].w + (xb[c].w + bv.w);
            ntStore4(out_bda + b0 + col, A[c][0], A[c][1], A[c][2], A[c][3]);
            ntStore4(out_bda + b1 + col, B[c][0], B[c][1], B[c][2], B[c][3]);
            s0 += (A[c][0] + A[c][1]) + (A[c][2] + A[c][3]);
            s1 += (B[c][0] + B[c][1]) + (B[c][2] + B[c][3]);
        }

        // ---- mean: two independent butterflies, explicitly interleaved ----
#pragma unroll
        for (int off = 1; off < 64; off <<= 1) {
            s0 += __shfl_xor(s0, off);
            s1 += __shfl_xor(s1, off);
        }
        const float mu0 = s0 * INV_H;
        const float mu1 = s1 * INV_H;

        // ---- variance, two-pass, both rows ----
        float ss0 = 0.0f, ss1 = 0.0f;
#pragma unroll
        for (int c = 0; c < CHUNKS; ++c) {
#pragma unroll
            for (int j = 0; j < 4; ++j) {
                A[c][j] -= mu0; ss0 += A[c][j] * A[c][j];
                B[c][j] -= mu1; ss1 += B[c][j] * B[c][j];
            }
        }
#pragma unroll
        for (int off = 1; off < 64; off <<= 1) {
            ss0 += __shfl_xor(ss0, off);
            ss1 += __shfl_xor(ss1, off);
        }
        const float rs0 = 1.0f / sqrtf(ss0 * INV_H + EPS);
        const float rs1 = 1.0f / sqrtf(ss1 * INV_H + EPS);

        // ---- normalize + affine + fp8 + store; gamma/beta shared per chunk ----
#pragma unroll
        for (int c = 0; c < CHUNKS; ++c) {
            const int col = col0 + c * 256;
            const float4 gv = *reinterpret_cast<const float4*>(gamma + col);
            const float4 tv = *reinterpret_cast<const float4*>(beta + col);
            quantChunk(A[c], rs0, gv, tv, out_q + b0 + col, localAmax);
            quantChunk(B[c], rs1, gv, tv, out_q + b1 + col, localAmax);
        }
    }

    // tail (odd n_rows only; never runs in this benchmark)
    for (int row = 2 * pairs + gw; row < n_rows; row += gwaves)
        processOneRow(row, col0, x, residual, bias, gamma, beta,
                      out_bda, out_q, localAmax);

    // ---- block amax -> one device-scope atomic per block ----
    float m = waveReduceMax(localAmax);
    if (lane == 0) red[wid] = m;
    __syncthreads();
    if (tid == 0) {
        const float bm = fmaxf(fmaxf(red[0], red[1]), fmaxf(red[2], red[3]));
        atomicMax(out_amax, __float_as_uint(bm));   // all values >= 0
    }
}

extern "C" void kernel_launch(void* const* d_in, const int* in_sizes, int n_in,
                              void* d_out, int out_size, void* d_ws, size_t ws_size,
                              hipStream_t stream) {
    const float* x        = (const float*)d_in[0];
    const float* bias     = (const float*)d_in[1];
    const float* residual = (const float*)d_in[2];
    const float* gamma    = (const float*)d_in[3];
    const float* beta     = (const float*)d_in[4];

    const int n_elems = in_sizes[0];          // B*S*H
    const int n_rows = n_elems / H;           // 32768

    float* out_bda = (float*)d_out;
    float* out_q   = out_bda + (size_t)n_elems;
    unsigned int* out_amax = (unsigned int*)(out_bda + 2 * (size_t)n_elems);

    // zero the amax slot each launch (deterministic across graph replays)
    hipMemsetAsync((void*)out_amax, 0, sizeof(unsigned int), stream);

    // 2048 blocks x 4 waves = 8192 waves, 2 rows/wave/iter -> 2 iterations.
    int blocks = (n_rows / 2 + 3) / 4;
    if (blocks > 2048) blocks = 2048;

    fused_bda_ln_fp8<<<blocks, 256, 0, stream>>>(
        x, bias, residual, gamma, beta, out_bda, out_q, out_amax, n_rows);
}